// Round 9
// baseline (205.291 us; speedup 1.0000x reference)
//
#include <hip/hip_runtime.h>
#include <hip/hip_bf16.h>

#define M_DIM 32768
#define K_DIM 1024
#define N_POOL 1024

#define BM 256
#define BN 256
#define BK 64
#define KTILES (K_DIM / BK)   // 16

typedef __attribute__((ext_vector_type(8))) short bf16x8;
typedef __attribute__((ext_vector_type(4))) float f32x4;

typedef __attribute__((address_space(3))) unsigned int lds_uint;
typedef const __attribute__((address_space(1))) unsigned int g_uint;

__device__ __forceinline__ unsigned short f2bf(float f) {
    unsigned int u = __builtin_bit_cast(unsigned int, f);
    unsigned int lsb = (u >> 16) & 1u;
    u += 0x7fffu + lsb;
    return (unsigned short)(u >> 16);
}

__device__ __forceinline__ unsigned int f2bf2(float lo, float hi) {
    // packed RNE cvt — compiler emits v_cvt_pk_bf16_f32
    __hip_bfloat162 h2 = __float22bfloat162_rn(make_float2(lo, hi));
    union { __hip_bfloat162 h; unsigned int u; } c;
    c.h = h2;
    return c.u;
}

// ---------------- prep: fold avgpool(k=4) into weight/bias, cast to bf16 ----
__global__ __launch_bounds__(256) void prep_kernel(
        const float* __restrict__ W, const float* __restrict__ b,
        unsigned short* __restrict__ wp, float* __restrict__ bp) {
    int n = blockIdx.x;
    int t = threadIdx.x;
    const float4* r0 = (const float4*)(W + (size_t)(4 * n + 0) * K_DIM);
    const float4* r1 = (const float4*)(W + (size_t)(4 * n + 1) * K_DIM);
    const float4* r2 = (const float4*)(W + (size_t)(4 * n + 2) * K_DIM);
    const float4* r3 = (const float4*)(W + (size_t)(4 * n + 3) * K_DIM);
    float4 a0 = r0[t], a1 = r1[t], a2 = r2[t], a3 = r3[t];
    float sx = (a0.x + a1.x + a2.x + a3.x) * 0.25f;
    float sy = (a0.y + a1.y + a2.y + a3.y) * 0.25f;
    float sz = (a0.z + a1.z + a2.z + a3.z) * 0.25f;
    float sw = (a0.w + a1.w + a2.w + a3.w) * 0.25f;
    ushort4 h;
    h.x = f2bf(sx); h.y = f2bf(sy); h.z = f2bf(sz); h.w = f2bf(sw);
    *(ushort4*)&wp[(size_t)n * K_DIM + t * 4] = h;
    if (t == 0)
        bp[n] = 0.25f * (b[4 * n] + b[4 * n + 1] + b[4 * n + 2] + b[4 * n + 3]);
}

// ============ 256x256 4-phase GEMM, m201-style transient fragments ==========
// LDS rows [r][BK] bf16 (128 B), 16B-chunk col swizzled: slot = c16 ^ (r&7).
// A: reg-staged f32 (issue@P0, cvt+swizzled ds_write@P2 -> counted vmcnt).
// B: global_load_lds (issue@P1), source pre-swizzled, linear LDS dest.
// Single vmcnt(0)+lgkmcnt(0) drain per K-tile at P3 (loads ~3 phases old).

__device__ __forceinline__ bf16x8 ldfrag(const unsigned short* base, int r, int c16) {
    return *(const bf16x8*)&base[r * 64 + (((c16) ^ (r & 7)) << 3)];
}

struct AStage { float4 av[8]; };

__device__ __forceinline__ void a_issue(AStage& s, const float4* __restrict__ xg,
                                        int m0, int ktgt, int tid) {
#pragma unroll
    for (int j = 0; j < 4; ++j) {
        int p = j * 512 + tid;            // 16B-out-chunk index within tile
        int row = p >> 3, c16 = p & 7;
        size_t base = (size_t)(m0 + row) * 256 + ktgt * 16 + c16 * 2;
        s.av[2 * j]     = xg[base];
        s.av[2 * j + 1] = xg[base + 1];
    }
}

__device__ __forceinline__ void a_write(const AStage& s, unsigned short* An, int tid) {
#pragma unroll
    for (int j = 0; j < 4; ++j) {
        int p = j * 512 + tid;
        int row = p >> 3, c16 = p & 7;
        union { bf16x8 v; unsigned int u[4]; } pk;
        pk.u[0] = f2bf2(s.av[2 * j].x,     s.av[2 * j].y);
        pk.u[1] = f2bf2(s.av[2 * j].z,     s.av[2 * j].w);
        pk.u[2] = f2bf2(s.av[2 * j + 1].x, s.av[2 * j + 1].y);
        pk.u[3] = f2bf2(s.av[2 * j + 1].z, s.av[2 * j + 1].w);
        *(bf16x8*)&An[row * 64 + ((c16 ^ (row & 7)) << 3)] = pk.v;
    }
}

__device__ __forceinline__ void b_issue(const unsigned short* __restrict__ wp,
                                        unsigned short* Bn, int n0, int ktgt,
                                        int wid, int lane) {
#pragma unroll
    for (int i = 0; i < 4; ++i) {
        int row0 = (wid * 4 + i) * 8;
        int n = n0 + row0 + (lane >> 3);
        int g = (lane & 7) ^ (lane >> 3);   // swizzled source chunk
        __builtin_amdgcn_global_load_lds(
            (g_uint*)(wp + (size_t)n * K_DIM + ktgt * BK + g * 8),
            (lds_uint*)&Bn[row0 * 64], 16, 0, 0);
    }
}

__global__ __launch_bounds__(512, 1) void gemm_kernel(
        const float* __restrict__ x, const unsigned short* __restrict__ wp,
        const float* __restrict__ bp, float* __restrict__ partial) {
    __shared__ unsigned short As[2][BM * BK];   // 2 x 32 KB
    __shared__ unsigned short Bs[2][BN * BK];   // 2 x 32 KB

    // XCD-chunked swizzle (512 blocks % 8 == 0 -> bijective)
    int bid = blockIdx.x;
    int wg = (bid & 7) * 64 + (bid >> 3);
    int nblk = wg & 3;
    int mblk = wg >> 2;
    int m0 = mblk * BM;
    int n0 = nblk * BN;

    int tid = threadIdx.x;
    int lane = tid & 63;
    int wid = tid >> 6;              // 0..7
    int wm = wid >> 2, wn = wid & 3; // 2 x 4 wave grid; wave tile 128x64
    int rl = lane & 15;
    int q = lane >> 4;               // 0..3

    f32x4 acc[8][4];
#pragma unroll
    for (int i = 0; i < 8; ++i)
#pragma unroll
        for (int j = 0; j < 4; ++j)
            acc[i][j] = (f32x4)(0.0f);

    const float4* xg = (const float4*)x;

    // ---- prologue: stage tile 0 into buf 0, full drain, barrier ----
    {
        AStage sa;
        a_issue(sa, xg, m0, 0, tid);
        b_issue(wp, Bs[0], n0, 0, wid, lane);
        a_write(sa, As[0], tid);
        asm volatile("s_waitcnt vmcnt(0) lgkmcnt(0)" ::: "memory");
        __builtin_amdgcn_sched_barrier(0);
        __builtin_amdgcn_s_barrier();
    }

#pragma unroll 1
    for (int kt = 0; kt < KTILES; ++kt) {
        const int cur = kt & 1;
        const bool stage = (kt + 1) < KTILES;
        const unsigned short* Ac = As[cur];
        const unsigned short* Bc = Bs[cur];
        unsigned short* An = As[cur ^ 1];
        unsigned short* Bn = Bs[cur ^ 1];

        AStage sa;
        bf16x8 af[4][2];   // current m-half frags (reused registers per half)

        // ================= P0: af(m-half0) + bf(n-half0), A issue =============
#pragma unroll
        for (int mi = 0; mi < 4; ++mi)
#pragma unroll
            for (int ks = 0; ks < 2; ++ks)
                af[mi][ks] = ldfrag(Ac, wm * 128 + mi * 16 + rl, ks * 4 + q);
        {
            bf16x8 bf[2][2];
#pragma unroll
            for (int nf = 0; nf < 2; ++nf)
#pragma unroll
                for (int ks = 0; ks < 2; ++ks)
                    bf[nf][ks] = ldfrag(Bc, wn * 64 + nf * 16 + rl, ks * 4 + q);
            if (stage) a_issue(sa, xg, m0, kt + 1, tid);
            __builtin_amdgcn_s_barrier();
            __builtin_amdgcn_s_setprio(1);
#pragma unroll
            for (int ks = 0; ks < 2; ++ks)
#pragma unroll
                for (int mi = 0; mi < 4; ++mi)
#pragma unroll
                    for (int nf = 0; nf < 2; ++nf)
                        acc[mi][nf] = __builtin_amdgcn_mfma_f32_16x16x32_bf16(
                            af[mi][ks], bf[nf][ks], acc[mi][nf], 0, 0, 0);
            __builtin_amdgcn_s_setprio(0);
            __builtin_amdgcn_s_barrier();
        }

        // ================= P1: bf(n-half1), B issue ===========================
        {
            bf16x8 bf[2][2];
#pragma unroll
            for (int nf = 0; nf < 2; ++nf)
#pragma unroll
                for (int ks = 0; ks < 2; ++ks)
                    bf[nf][ks] = ldfrag(Bc, wn * 64 + 32 + nf * 16 + rl, ks * 4 + q);
            if (stage) b_issue(wp, Bn, n0, kt + 1, wid, lane);
            __builtin_amdgcn_s_barrier();
            __builtin_amdgcn_s_setprio(1);
#pragma unroll
            for (int ks = 0; ks < 2; ++ks)
#pragma unroll
                for (int mi = 0; mi < 4; ++mi)
#pragma unroll
                    for (int nf = 0; nf < 2; ++nf)
                        acc[mi][2 + nf] = __builtin_amdgcn_mfma_f32_16x16x32_bf16(
                            af[mi][ks], bf[nf][ks], acc[mi][2 + nf], 0, 0, 0);
            __builtin_amdgcn_s_setprio(0);
            __builtin_amdgcn_s_barrier();
        }

        // ================= P2: af(m-half1) + bf(n-half0 re-read), A write =====
#pragma unroll
        for (int mi = 0; mi < 4; ++mi)
#pragma unroll
            for (int ks = 0; ks < 2; ++ks)
                af[mi][ks] = ldfrag(Ac, wm * 128 + 64 + mi * 16 + rl, ks * 4 + q);
        {
            bf16x8 bf[2][2];
#pragma unroll
            for (int nf = 0; nf < 2; ++nf)
#pragma unroll
                for (int ks = 0; ks < 2; ++ks)
                    bf[nf][ks] = ldfrag(Bc, wn * 64 + nf * 16 + rl, ks * 4 + q);
            if (stage) a_write(sa, An, tid);   // counted vmcnt: B glds stay in flight
            __builtin_amdgcn_s_barrier();
            __builtin_amdgcn_s_setprio(1);
#pragma unroll
            for (int ks = 0; ks < 2; ++ks)
#pragma unroll
                for (int mi = 0; mi < 4; ++mi)
#pragma unroll
                    for (int nf = 0; nf < 2; ++nf)
                        acc[4 + mi][nf] = __builtin_amdgcn_mfma_f32_16x16x32_bf16(
                            af[mi][ks], bf[nf][ks], acc[4 + mi][nf], 0, 0, 0);
            __builtin_amdgcn_s_setprio(0);
            __builtin_amdgcn_s_barrier();
        }

        // ================= P3: bf(n-half1 re-read), tile-boundary drain =======
        {
            bf16x8 bf[2][2];
#pragma unroll
            for (int nf = 0; nf < 2; ++nf)
#pragma unroll
                for (int ks = 0; ks < 2; ++ks)
                    bf[nf][ks] = ldfrag(Bc, wn * 64 + 32 + nf * 16 + rl, ks * 4 + q);
            __builtin_amdgcn_s_barrier();
            __builtin_amdgcn_s_setprio(1);
#pragma unroll
            for (int ks = 0; ks < 2; ++ks)
#pragma unroll
                for (int mi = 0; mi < 4; ++mi)
#pragma unroll
                    for (int nf = 0; nf < 2; ++nf)
                        acc[4 + mi][2 + nf] = __builtin_amdgcn_mfma_f32_16x16x32_bf16(
                            af[mi][ks], bf[nf][ks], acc[4 + mi][2 + nf], 0, 0, 0);
            __builtin_amdgcn_s_setprio(0);
            // B glds (issued P1) + A ds_writes (P2) must land before buffer swap
            asm volatile("s_waitcnt vmcnt(0) lgkmcnt(0)" ::: "memory");
            __builtin_amdgcn_sched_barrier(0);
            __builtin_amdgcn_s_barrier();
        }
    }

    // ---- epilogue: bias + tanh-gelu*2 + row-max over wave's 64-col slice ----
    float bv[4];
#pragma unroll
    for (int ni = 0; ni < 4; ++ni)
        bv[ni] = bp[n0 + wn * 64 + ni * 16 + rl];

    const float GC = 0.7978845608028654f;
#pragma unroll
    for (int mi = 0; mi < 8; ++mi) {
#pragma unroll
        for (int j = 0; j < 4; ++j) {
            float mx = -3.4e38f;
#pragma unroll
            for (int ni = 0; ni < 4; ++ni) {
                float y = acc[mi][ni][j] + bv[ni];
                float z = GC * (y + 0.044715f * y * y * y);
                float e = __expf(2.0f * z);
                float th = 1.0f - 2.0f / (e + 1.0f);   // tanh(z)
                float g = y * (1.0f + th);             // 0.5*(1+tanh)*y*SCALE(2)
                mx = fmaxf(mx, g);
            }
#pragma unroll
            for (int s = 1; s < 16; s <<= 1)
                mx = fmaxf(mx, __shfl_xor(mx, s, 64));
            if (rl == 0) {
                int grow = m0 + wm * 128 + mi * 16 + q * 4 + j;
                partial[(size_t)(nblk * 4 + wn) * M_DIM + grow] = mx;
            }
        }
    }
}

// ---------------- final reduce: max over 16 column-chunks -------------------
__global__ __launch_bounds__(256) void reduce_kernel(
        const float* __restrict__ partial, float* __restrict__ out) {
    int m = blockIdx.x * 256 + threadIdx.x;
    float mx = -3.4e38f;
#pragma unroll
    for (int c = 0; c < 16; ++c)
        mx = fmaxf(mx, partial[(size_t)c * M_DIM + m]);
    out[m] = mx;
}

extern "C" void kernel_launch(void* const* d_in, const int* in_sizes, int n_in,
                              void* d_out, int out_size, void* d_ws, size_t ws_size,
                              hipStream_t stream) {
    const float* x = (const float*)d_in[0];
    const float* W = (const float*)d_in[1];
    const float* bias = (const float*)d_in[2];
    float* out = (float*)d_out;

    unsigned short* wp = (unsigned short*)d_ws;                         // 2 MB
    float* bp = (float*)((char*)d_ws + 2 * 1024 * 1024);                // 4 KB
    float* partial = (float*)((char*)d_ws + 2 * 1024 * 1024 + 4096);    // 2 MB

    prep_kernel<<<N_POOL, 256, 0, stream>>>(W, bias, wp, bp);
    gemm_kernel<<<(M_DIM / BM) * (N_POOL / BN), 512, 0, stream>>>(x, wp, bp, partial);
    reduce_kernel<<<M_DIM / 256, 256, 0, stream>>>(partial, out);
}

// Round 10
// 124.024 us; speedup vs baseline: 1.6553x; 1.6553x over previous
//
#include <hip/hip_runtime.h>
#include <hip/hip_bf16.h>

#define M_DIM 32768
#define K_DIM 1024
#define N_POOL 1024

#define BM 128
#define BN 128
#define BK 64
#define KTILES (K_DIM / BK)   // 16

typedef __attribute__((ext_vector_type(8))) short bf16x8;
typedef __attribute__((ext_vector_type(4))) float f32x4;

typedef __attribute__((address_space(3))) unsigned int lds_uint;
typedef const __attribute__((address_space(1))) unsigned int g_uint;

__device__ __forceinline__ unsigned short f2bf(float f) {
    unsigned int u = __builtin_bit_cast(unsigned int, f);
    unsigned int lsb = (u >> 16) & 1u;
    u += 0x7fffu + lsb;
    return (unsigned short)(u >> 16);
}

__device__ __forceinline__ unsigned int f2bf2(float lo, float hi) {
    // packed RNE cvt — compiler emits v_cvt_pk_bf16_f32
    __hip_bfloat162 h2 = __float22bfloat162_rn(make_float2(lo, hi));
    union { __hip_bfloat162 h; unsigned int u; } c;
    c.h = h2;
    return c.u;
}

// ---------------- prep: fold avgpool(k=4) into weight/bias, cast to bf16 ----
__global__ __launch_bounds__(256) void prep_kernel(
        const float* __restrict__ W, const float* __restrict__ b,
        unsigned short* __restrict__ wp, float* __restrict__ bp) {
    int n = blockIdx.x;
    int t = threadIdx.x;
    const float4* r0 = (const float4*)(W + (size_t)(4 * n + 0) * K_DIM);
    const float4* r1 = (const float4*)(W + (size_t)(4 * n + 1) * K_DIM);
    const float4* r2 = (const float4*)(W + (size_t)(4 * n + 2) * K_DIM);
    const float4* r3 = (const float4*)(W + (size_t)(4 * n + 3) * K_DIM);
    float4 a0 = r0[t], a1 = r1[t], a2 = r2[t], a3 = r3[t];
    float sx = (a0.x + a1.x + a2.x + a3.x) * 0.25f;
    float sy = (a0.y + a1.y + a2.y + a3.y) * 0.25f;
    float sz = (a0.z + a1.z + a2.z + a3.z) * 0.25f;
    float sw = (a0.w + a1.w + a2.w + a3.w) * 0.25f;
    ushort4 h;
    h.x = f2bf(sx); h.y = f2bf(sy); h.z = f2bf(sz); h.w = f2bf(sw);
    *(ushort4*)&wp[(size_t)n * K_DIM + t * 4] = h;
    if (t == 0)
        bp[n] = 0.25f * (b[4 * n] + b[4 * n + 1] + b[4 * n + 2] + b[4 * n + 3]);
}

// ---- conv: x f32 -> bf16, tile-major, LDS-swizzle pre-baked ----------------
// xb layout: for m-tile mblk (128 rows), k-tile kt (64 cols): contiguous 16 KB
// block at ushort offset (mblk*16+kt)*8192; within block, chunk (r, c16) at
// r*64 + ((c16 ^ (r&7))<<3).  GEMM's glds then copies blocks linearly and the
// swizzled ds_read finds exactly this layout (both-sides involution, rule #21).
__global__ __launch_bounds__(256) void conv_kernel(
        const float* __restrict__ x, unsigned short* __restrict__ xb) {
    int bid = blockIdx.x;            // 2048 blocks
    int mblk = bid >> 3;
    int sub = bid & 7;
    int m0 = mblk * BM;
    int tid = threadIdx.x;
    size_t tb = (size_t)mblk * 16 * 8192;
#pragma unroll
    for (int j = 0; j < 8; ++j) {
        int p = sub * 2048 + j * 256 + tid;    // 0..16383
        int kt = p >> 10;
        int r = (p >> 3) & 127;
        int c16 = p & 7;
        const float4* src = (const float4*)(x + (size_t)(m0 + r) * K_DIM + kt * 64 + c16 * 8);
        float4 a = src[0], b = src[1];
        union { bf16x8 v; unsigned int u[4]; } pk;
        pk.u[0] = f2bf2(a.x, a.y);
        pk.u[1] = f2bf2(a.z, a.w);
        pk.u[2] = f2bf2(b.x, b.y);
        pk.u[3] = f2bf2(b.z, b.w);
        *(bf16x8*)&xb[tb + (size_t)kt * 8192 + r * 64 + ((c16 ^ (r & 7)) << 3)] = pk.v;
    }
}

// ================= 128x128 GEMM, m97-exact structure =======================
// Both operands staged via global_load_lds width=16, linear dest.
// A source: pre-converted pre-swizzled xb (contiguous per tile).
// B source: wp with per-lane pre-swizzled chunk (as R2, 0 conflicts measured).
// 2 __syncthreads per K-tile, compiler-managed waits. No asm, no setprio.

__device__ __forceinline__ bf16x8 ldfrag(const unsigned short* base, int r, int c16) {
    return *(const bf16x8*)&base[r * 64 + (((c16) ^ (r & 7)) << 3)];
}

__device__ __forceinline__ void a_issue(const unsigned short* __restrict__ xb,
                                        unsigned short* As, int mblk, int kt,
                                        int wid, int lane) {
    size_t base = ((size_t)mblk * 16 + kt) * 8192;
#pragma unroll
    for (int i = 0; i < 4; ++i) {
        int c = i * 256 + wid * 64 + lane;   // 16B-chunk index 0..1023
        __builtin_amdgcn_global_load_lds(
            (g_uint*)(xb + base + (size_t)c * 8),
            (lds_uint*)&As[(i * 256 + wid * 64) * 8], 16, 0, 0);
    }
}

__device__ __forceinline__ void b_issue(const unsigned short* __restrict__ wp,
                                        unsigned short* Bs, int n0, int kt,
                                        int wid, int lane) {
#pragma unroll
    for (int i = 0; i < 4; ++i) {
        int ii = wid * 4 + i;
        int rsub = lane >> 3;
        int g = (lane & 7) ^ rsub;           // swizzled source chunk
        int n = n0 + ii * 8 + rsub;
        __builtin_amdgcn_global_load_lds(
            (g_uint*)(wp + (size_t)n * K_DIM + kt * BK + g * 8),
            (lds_uint*)&Bs[ii * 512], 16, 0, 0);
    }
}

__global__ __launch_bounds__(256, 2) void gemm_kernel(
        const unsigned short* __restrict__ xb, const unsigned short* __restrict__ wp,
        const float* __restrict__ bp, float* __restrict__ partial) {
    __shared__ unsigned short As[BM * BK];   // 16 KB
    __shared__ unsigned short Bs[BN * BK];   // 16 KB

    // XCD-chunked swizzle: 2048 blocks, 8 XCDs, 256 each (bijective)
    int bid = blockIdx.x;
    int wg = (bid & 7) * 256 + (bid >> 3);
    int nblk = wg & 7;
    int mblk = wg >> 3;
    int n0 = nblk * BN;

    int tid = threadIdx.x;
    int lane = tid & 63;
    int wid = tid >> 6;
    int wr = wid >> 1, wc = wid & 1;   // 2x2 wave grid, each wave 64x64

    f32x4 acc[4][4];
#pragma unroll
    for (int i = 0; i < 4; ++i)
#pragma unroll
        for (int j = 0; j < 4; ++j)
            acc[i][j] = (f32x4)(0.0f);

#pragma unroll 1
    for (int kt = 0; kt < KTILES; ++kt) {
        __syncthreads();   // previous tile's LDS reads done
        a_issue(xb, As, mblk, kt, wid, lane);
        b_issue(wp, Bs, n0, kt, wid, lane);
        __syncthreads();   // compiler drains vmcnt before barrier

        // ---- compute: 2 x (8 swizzled ds_read_b128 + 16 MFMA) ----
#pragma unroll
        for (int kk = 0; kk < BK; kk += 32) {
            int c16r = (kk >> 3) + (lane >> 4);
            bf16x8 af[4], bff[4];
#pragma unroll
            for (int mi = 0; mi < 4; ++mi) {
                int r = wr * 64 + mi * 16 + (lane & 15);
                af[mi] = ldfrag(As, r, c16r);
            }
#pragma unroll
            for (int ni = 0; ni < 4; ++ni) {
                int r = wc * 64 + ni * 16 + (lane & 15);
                bff[ni] = ldfrag(Bs, r, c16r);
            }
#pragma unroll
            for (int mi = 0; mi < 4; ++mi)
#pragma unroll
                for (int ni = 0; ni < 4; ++ni)
                    acc[mi][ni] = __builtin_amdgcn_mfma_f32_16x16x32_bf16(
                        af[mi], bff[ni], acc[mi][ni], 0, 0, 0);
        }
    }

    // ---- epilogue: bias + tanh-gelu*2 + row-max over this 64-col slice ----
    int m0 = mblk * BM;
    float bv[4];
#pragma unroll
    for (int ni = 0; ni < 4; ++ni)
        bv[ni] = bp[n0 + wc * 64 + ni * 16 + (lane & 15)];

    const float GC = 0.7978845608028654f;
#pragma unroll
    for (int mi = 0; mi < 4; ++mi) {
#pragma unroll
        for (int j = 0; j < 4; ++j) {
            float mx = -3.4e38f;
#pragma unroll
            for (int ni = 0; ni < 4; ++ni) {
                float y = acc[mi][ni][j] + bv[ni];
                float z = GC * (y + 0.044715f * y * y * y);
                float e = __expf(2.0f * z);
                float th = 1.0f - 2.0f / (e + 1.0f);   // tanh(z)
                float g = y * (1.0f + th);             // 0.5*(1+tanh)*y*SCALE(2)
                mx = fmaxf(mx, g);
            }
#pragma unroll
            for (int s = 1; s < 16; s <<= 1)
                mx = fmaxf(mx, __shfl_xor(mx, s, 64));
            if ((lane & 15) == 0) {
                int grow = m0 + wr * 64 + mi * 16 + (lane >> 4) * 4 + j;
                partial[(size_t)(nblk * 2 + wc) * M_DIM + grow] = mx;
            }
        }
    }
}

// ---------------- final reduce: max over 16 column-chunks -------------------
__global__ __launch_bounds__(256) void reduce_kernel(
        const float* __restrict__ partial, float* __restrict__ out) {
    int m = blockIdx.x * 256 + threadIdx.x;
    float mx = -3.4e38f;
#pragma unroll
    for (int c = 0; c < 16; ++c)
        mx = fmaxf(mx, partial[(size_t)c * M_DIM + m]);
    out[m] = mx;
}

extern "C" void kernel_launch(void* const* d_in, const int* in_sizes, int n_in,
                              void* d_out, int out_size, void* d_ws, size_t ws_size,
                              hipStream_t stream) {
    const float* x = (const float*)d_in[0];
    const float* W = (const float*)d_in[1];
    const float* bias = (const float*)d_in[2];
    float* out = (float*)d_out;

    unsigned short* wp = (unsigned short*)d_ws;                          // 2 MB
    float* bp = (float*)((char*)d_ws + 2 * 1024 * 1024);                 // 4 KB
    float* partial = (float*)((char*)d_ws + 2 * 1024 * 1024 + 4096);     // 2 MB
    unsigned short* xb = (unsigned short*)((char*)d_ws + 8 * 1024 * 1024); // 64 MB

    conv_kernel<<<2048, 256, 0, stream>>>(x, xb);
    prep_kernel<<<N_POOL, 256, 0, stream>>>(W, bias, wp, bp);
    gemm_kernel<<<(M_DIM / BM) * (N_POOL / BN), 256, 0, stream>>>(xb, wp, bp, partial);
    reduce_kernel<<<M_DIM / 256, 256, 0, stream>>>(partial, out);
}